// Round 1
// baseline (1372.282 us; speedup 1.0000x reference)
//
#include <hip/hip_runtime.h>

// IndRNN: two layers of (GEMM pre-projection + elementwise scan).
//   T=1024, B=64, I=512, H=2048.
// Pipeline (needs ~330 MiB of d_ws):
//   cvt x->fp16, w_ih0->fp16, w_ih1->fp16
//   GEMM0: pre0[65536,2048] (fp16, in ws) = x16[65536,512] * w0_16^T + b0
//   scan0: in-place on pre0 (fp32 state in regs) -> h0 fp16
//   GEMM1: pre1 = h0 * w1_16^T + b1  -> written fp32 directly to d_out
//   scan1: in-place fp32 on d_out

#define T_SEQ 1024
#define NB 64
#define NI 512
#define NH 2048
#define BH (NB * NH)          // 131072 channels per timestep
#define M_ROWS (T_SEQ * NB)   // 65536 GEMM rows

typedef _Float16 f16;
typedef __attribute__((ext_vector_type(8))) _Float16 f16x8;
typedef __attribute__((ext_vector_type(4))) _Float16 f16x4;
typedef __attribute__((ext_vector_type(4))) float f32x4;

__device__ __forceinline__ void gload_lds16(const void* g, void* lds) {
  __builtin_amdgcn_global_load_lds(
      (const __attribute__((address_space(1))) unsigned int*)g,
      (__attribute__((address_space(3))) unsigned int*)lds,
      16, 0, 0);
}

// ---------------- fp32 -> fp16 conversion (vectorized x4) ----------------
__global__ __launch_bounds__(256)
void cvt_f16x4(const float* __restrict__ in, f16* __restrict__ out, int n4) {
  int i = blockIdx.x * blockDim.x + threadIdx.x;
  const int stride = gridDim.x * blockDim.x;
  for (; i < n4; i += stride) {
    f32x4 v = ((const f32x4*)in)[i];
    f16x4 h;
    h[0] = (f16)v[0]; h[1] = (f16)v[1]; h[2] = (f16)v[2]; h[3] = (f16)v[3];
    ((f16x4*)out)[i] = h;
  }
}

// ---------------- GEMM: C[M,N] = A[M,K] * Bt[N,K]^T + bias ----------------
// m97-style: 128x128 block tile, BK=32, 4 waves each computing a 64x64
// quadrant via 4x4 grid of 16x16x32 f16 MFMAs. global_load_lds width=16
// staging (linear LDS), 2 barriers per K-step.
template <int K, typename OutT>
__global__ __launch_bounds__(256)
void gemm_bt(const f16* __restrict__ A, const f16* __restrict__ Bt,
             const float* __restrict__ bias, OutT* __restrict__ C,
             int M, int N) {
  constexpr int BM = 128, BN = 128, BK = 32;
  __shared__ f16 As[BM * BK];   // [128][32] row-major, linear (gload_lds req)
  __shared__ f16 Bs[BN * BK];

  const int tid  = threadIdx.x;
  const int wid  = tid >> 6;
  const int lane = tid & 63;
  const long m0 = (long)blockIdx.y * BM;   // N-blocks fastest => A-panel L2 reuse
  const long n0 = (long)blockIdx.x * BN;

  // --- staging addresses: wave w stages rows 32w..32w+31 of A and Bt ---
  // per instruction: 64 lanes x 16B = 16 rows x (4 x 8 halves)
  const int srow = (wid << 5) + (lane >> 2);
  const int sk   = (lane & 3) * 8;
  const f16* gA = A  + (m0 + srow) * K + sk;
  const f16* gB = Bt + (n0 + srow) * K + sk;
  f16* lA = As + (wid << 5) * BK;   // wave-uniform LDS base (+ lane*16B by HW)
  f16* lB = Bs + (wid << 5) * BK;

  // --- fragment addressing ---
  const int lrow = lane & 15;        // row (A) / col (B) within 16
  const int lk   = (lane >> 4) * 8;  // contiguous k-octet per 16-lane group
  const int wr = (wid >> 1) * 64;    // wave quadrant in 128x128 tile
  const int wc = (wid & 1) * 64;

  f32x4 acc[4][4] = {};

  for (int k0 = 0; k0 < K; k0 += BK) {
    gload_lds16(gA,                 lA);
    gload_lds16(gA + (size_t)16 * K, lA + 16 * BK);
    gload_lds16(gB,                 lB);
    gload_lds16(gB + (size_t)16 * K, lB + 16 * BK);
    gA += BK; gB += BK;
    __syncthreads();   // compiler emits vmcnt(0) drain before s_barrier

    f16x8 af[4], bf[4];
#pragma unroll
    for (int mt = 0; mt < 4; ++mt)
      af[mt] = *(const f16x8*)(As + (wr + mt * 16 + lrow) * BK + lk);
#pragma unroll
    for (int nt = 0; nt < 4; ++nt)
      bf[nt] = *(const f16x8*)(Bs + (wc + nt * 16 + lrow) * BK + lk);
#pragma unroll
    for (int mt = 0; mt < 4; ++mt)
#pragma unroll
      for (int nt = 0; nt < 4; ++nt)
        acc[mt][nt] = __builtin_amdgcn_mfma_f32_16x16x32_f16(
            af[mt], bf[nt], acc[mt][nt], 0, 0, 0);
    __syncthreads();
  }

  // --- epilogue: D layout col=lane&15, row=(lane>>4)*4+j ---
  const int crow = wr + ((lane >> 4) << 2);
  const int ccol = wc + (lane & 15);
  float bv[4];
#pragma unroll
  for (int nt = 0; nt < 4; ++nt) bv[nt] = bias[n0 + ccol + nt * 16];
#pragma unroll
  for (int mt = 0; mt < 4; ++mt) {
#pragma unroll
    for (int j = 0; j < 4; ++j) {
      long r = m0 + crow + mt * 16 + j;
      OutT* cp = C + r * (long)N + n0 + ccol;
#pragma unroll
      for (int nt = 0; nt < 4; ++nt)
        cp[nt * 16] = (OutT)(acc[mt][nt][j] + bv[nt]);
    }
  }
}

// ---------------- in-place scan: h[t] = relu(p[t] + w*h[t-1]) ----------------
// One thread per (b,h) channel; fp32 recurrence state in registers; 4-deep
// software prefetch so ~8 loads/SIMD stay in flight (HBM latency hiding).
template <typename PT>
__global__ __launch_bounds__(256)
void scan_inplace(PT* __restrict__ P, const float* __restrict__ w_hh) {
  const int c = blockIdx.x * 256 + threadIdx.x;   // 0..BH-1
  const float w = w_hh[c & (NH - 1)];
  PT* p = P + c;
  float h = 0.f;
  float v0 = (float)p[0L * BH];
  float v1 = (float)p[1L * BH];
  float v2 = (float)p[2L * BH];
  float v3 = (float)p[3L * BH];
  for (int t = 0; t < T_SEQ; t += 4) {
    float n0 = 0.f, n1 = 0.f, n2 = 0.f, n3 = 0.f;
    if (t + 4 < T_SEQ) {
      const PT* q = p + (long)(t + 4) * BH;
      n0 = (float)q[0L * BH];
      n1 = (float)q[1L * BH];
      n2 = (float)q[2L * BH];
      n3 = (float)q[3L * BH];
    }
    h = fmaxf(fmaf(w, h, v0), 0.f); p[(long)(t + 0) * BH] = (PT)h;
    h = fmaxf(fmaf(w, h, v1), 0.f); p[(long)(t + 1) * BH] = (PT)h;
    h = fmaxf(fmaf(w, h, v2), 0.f); p[(long)(t + 2) * BH] = (PT)h;
    h = fmaxf(fmaf(w, h, v3), 0.f); p[(long)(t + 3) * BH] = (PT)h;
    v0 = n0; v1 = n1; v2 = n2; v3 = n3;
  }
}

extern "C" void kernel_launch(void* const* d_in, const int* in_sizes, int n_in,
                              void* d_out, int out_size, void* d_ws, size_t ws_size,
                              hipStream_t stream) {
  const float* x     = (const float*)d_in[0];   // [1024,64,512]
  const float* w_ih0 = (const float*)d_in[1];   // [2048,512]
  const float* w_hh0 = (const float*)d_in[2];   // [2048]
  const float* b0    = (const float*)d_in[3];   // [2048]
  const float* w_ih1 = (const float*)d_in[4];   // [2048,2048]
  const float* w_hh1 = (const float*)d_in[5];   // [2048]
  const float* b1    = (const float*)d_in[6];   // [2048]
  float* out = (float*)d_out;                   // [1024,64,2048]

  // workspace layout (bytes), all 256-aligned; total = 330 MiB
  char* ws = (char*)d_ws;
  f16* x16   = (f16*)(ws);                 // 33554432 halves = 64 MiB
  f16* w0_16 = (f16*)(ws + 67108864);      // 1048576 halves  =  2 MiB
  f16* w1_16 = (f16*)(ws + 69206016);      // 4194304 halves  =  8 MiB
  f16* P     = (f16*)(ws + 77594624);      // 65536*2048      = 256 MiB

  cvt_f16x4<<<2048, 256, 0, stream>>>(x,     x16,   33554432 / 4);
  cvt_f16x4<<<1024, 256, 0, stream>>>(w_ih0, w0_16, 1048576 / 4);
  cvt_f16x4<<<2048, 256, 0, stream>>>(w_ih1, w1_16, 4194304 / 4);

  dim3 grid(NH / 128, M_ROWS / 128);   // (16, 512): N fastest => A-panel reuse
  gemm_bt<NI, f16><<<grid, 256, 0, stream>>>(x16, w0_16, b0, P, M_ROWS, NH);
  scan_inplace<f16><<<BH / 256, 256, 0, stream>>>(P, w_hh0);
  gemm_bt<NH, float><<<grid, 256, 0, stream>>>(P, w1_16, b1, out, M_ROWS, NH);
  scan_inplace<float><<<BH / 256, 256, 0, stream>>>(out, w_hh1);
}

// Round 2
// 1158.545 us; speedup vs baseline: 1.1845x; 1.1845x over previous
//
#include <hip/hip_runtime.h>

// IndRNN: two layers of (GEMM pre-projection + elementwise scan).
//   T=1024, B=64, I=512, H=2048.
// R2: GEMMs ported to the 256^2 8-phase template (T2 swizzle + T3/T4 counted
// vmcnt + T5 setprio). 512 threads = 8 waves (2M x 4N, tiles interleaved by 16
// so quadrant phases map onto LDS half-tiles). LDS = 128 KiB (2 dbuf x 2 half
// x [128][64] f16 for A and B). Staging via global_load_lds w=16 with
// inverse-swizzled GLOBAL source + linear LDS dest (rule 21); reads apply
// byte ^= ((row&7)<<4) (conflict-free for 16-rows-at-one-slot ds_read_b128).

#define T_SEQ 1024
#define NB 64
#define NI 512
#define NH 2048
#define BH (NB * NH)
#define M_ROWS (T_SEQ * NB)

typedef _Float16 f16;
typedef __attribute__((ext_vector_type(8))) _Float16 f16x8;
typedef __attribute__((ext_vector_type(4))) _Float16 f16x4;
typedef __attribute__((ext_vector_type(4))) float f32x4;

__device__ __forceinline__ void gload_lds16(const f16* g, const f16* lds) {
  __builtin_amdgcn_global_load_lds(
      (const __attribute__((address_space(1))) unsigned int*)g,
      (__attribute__((address_space(3))) unsigned int*)lds, 16, 0, 0);
}
__device__ __forceinline__ void barrier_raw() {
  __builtin_amdgcn_sched_barrier(0);
  __builtin_amdgcn_s_barrier();
  __builtin_amdgcn_sched_barrier(0);
}
// rule 18: inline-asm lgkmcnt(0) needs a following sched_barrier(0)
#define LGKM0()                                        \
  do {                                                 \
    asm volatile("s_waitcnt lgkmcnt(0)" ::: "memory"); \
    __builtin_amdgcn_sched_barrier(0);                 \
  } while (0)
#define VMCNT4() asm volatile("s_waitcnt vmcnt(4)" ::: "memory")

// ---------------- fp32 -> fp16 conversion (vectorized x4) ----------------
__global__ __launch_bounds__(256)
void cvt_f16x4(const float* __restrict__ in, f16* __restrict__ out, int n4) {
  int i = blockIdx.x * blockDim.x + threadIdx.x;
  const int stride = gridDim.x * blockDim.x;
  for (; i < n4; i += stride) {
    f32x4 v = ((const f32x4*)in)[i];
    f16x4 h;
    h[0] = (f16)v[0]; h[1] = (f16)v[1]; h[2] = (f16)v[2]; h[3] = (f16)v[3];
    ((f16x4*)out)[i] = h;
  }
}

// ------- GEMM: C[M,2048] = A[M,K] * Bt[2048,K]^T + bias, 8-phase 256^2 -------
// Wave (wr,wc): wr=wid>>2 (2 M-groups), wc=wid&3 (4 N-groups).
// m-tile mt(0..7) -> C rows (2*mt+wr)*16; A-half = mt>>2 (interleave-by-16).
// n-tile nt(0..3) -> C cols (4*nt+wc)*16; B-half = nt>>1.
// Phases per K-tile: (m0,n0)(m0,n1)(m1,n1)(m1,n0); stages: A1(t+1), B0(t+1),
// A0(t+2), B1(t+2); vmcnt(4) at phase 3 only.
template <int K, typename OutT>
__global__ __launch_bounds__(512, 2)
void gemm8(const f16* __restrict__ A, const f16* __restrict__ Bt,
           const float* __restrict__ bias, OutT* __restrict__ C) {
  constexpr int NT = K / 64;
  __shared__ f16 sA[2][2][128 * 64];   // [buf][half][row 128][k 64]
  __shared__ f16 sB[2][2][128 * 64];

  const int tid = threadIdx.x, wid = tid >> 6, lane = tid & 63;
  int id = (int)blockIdx.x;
  id = (id & 7) * 256 + (id >> 3);          // XCD swizzle (2048 % 8 == 0)
  const int bn = id & 7, bm = id >> 3;
  const long m0 = (long)bm * 256, n0 = (long)bn * 256;

  const int wr = wid >> 2, wc = wid & 3;
  const int lrow = lane & 15, lk = (lane >> 4) * 8;

  // ds_read byte offsets: L = (tilebase) + ks*64 + T; phys = L ^ ((row&7)<<4).
  // row&7 == lrow&7 (tile bases are x16); xor bits 4-6 never carry out.
  const int xorv = (lrow & 7) << 4;
  const int TxA = (((wr * 16 + lrow) * 128) + lk * 2) ^ xorv;
  const int TxB = (((wc * 16 + lrow) * 128) + lk * 2) ^ xorv;

  auto ldA = [&](int buf, int mt, int ks) -> f16x8 {
    const char* p = (const char*)&sA[buf][mt >> 2][0];
    return *(const f16x8*)(p + (mt & 3) * 4096 + (TxA ^ (ks << 6)));
  };
  auto ldB = [&](int buf, int nt, int ks) -> f16x8 {
    const char* p = (const char*)&sB[buf][nt >> 1][0];
    return *(const f16x8*)(p + (nt & 1) * 8192 + (TxB ^ (ks << 6)));
  };

  // staging: LDS dest linear (base + lane*16 by HW); source pre-swizzled.
  // dest byte p = wid*1024 + i*8192 + lane*16 -> r = wid*8+(lane>>3)+i*64,
  // col element = ((lane&7)^((lane>>3)&7))*8.
  const int srow = wid * 8 + (lane >> 3);
  const int scol = ((lane & 7) ^ ((lane >> 3) & 7)) * 8;
  const int ldst = wid * 512;   // f16 elements; +4096 for inst 1

  auto stageA = [&](int buf, int h, int kt) {
    if (kt >= NT) kt = NT - 1;   // tail clamp: lands in a dead buffer
    const f16* g = A + (m0 + h * 128 + srow) * (long)K + kt * 64 + scol;
    gload_lds16(g,                &sA[buf][h][ldst]);
    gload_lds16(g + 64 * (long)K, &sA[buf][h][ldst + 4096]);
  };
  auto stageB = [&](int buf, int h, int kt) {
    if (kt >= NT) kt = NT - 1;
    const f16* g = Bt + (n0 + h * 128 + srow) * (long)K + kt * 64 + scol;
    gload_lds16(g,                &sB[buf][h][ldst]);
    gload_lds16(g + 64 * (long)K, &sB[buf][h][ldst + 4096]);
  };

  f32x4 acc[8][4] = {};
  f16x8 aR[4][2], bR[4][2];

#define MFMA16(MBASE, NBASE)                                                   \
  __builtin_amdgcn_s_setprio(1);                                               \
  _Pragma("unroll") for (int mi = 0; mi < 4; ++mi)                             \
      _Pragma("unroll") for (int ni = 0; ni < 2; ++ni)                         \
          _Pragma("unroll") for (int ks = 0; ks < 2; ++ks)                     \
              acc[MBASE + mi][NBASE + ni] =                                    \
                  __builtin_amdgcn_mfma_f32_16x16x32_f16(                      \
                      aR[mi][ks], bR[NBASE + ni][ks],                          \
                      acc[MBASE + mi][NBASE + ni], 0, 0, 0);                   \
  __builtin_amdgcn_s_setprio(0);

  // prologue — queue order must match steady state:
  // [A0(0), B1(0), A1(0), B0(0), A0(1), B1(1)], wait oldest 4 half-tiles.
  stageA(0, 0, 0);
  stageB(0, 1, 0);
  stageA(0, 1, 0);
  stageB(0, 0, 0);
  stageA(1, 0, 1);
  stageB(1, 1, 1);
  VMCNT4();
  barrier_raw();

  for (int t = 0; t < NT; ++t) {
    const int cur = t & 1, nxt = cur ^ 1;
    // ---- phase 0: quadrant (m0,n0); ds: A-half0 + B-half0; stage A1(t+1) ----
#pragma unroll
    for (int i = 0; i < 4; ++i) { aR[i][0] = ldA(cur, i, 0); aR[i][1] = ldA(cur, i, 1); }
#pragma unroll
    for (int i = 0; i < 2; ++i) { bR[i][0] = ldB(cur, i, 0); bR[i][1] = ldB(cur, i, 1); }
    stageA(nxt, 1, t + 1);
    barrier_raw();
    LGKM0();
    MFMA16(0, 0);
    barrier_raw();
    // ---- phase 1: (m0,n1); ds: B-half1; stage B0(t+1) ----
#pragma unroll
    for (int i = 0; i < 2; ++i) { bR[2 + i][0] = ldB(cur, 2 + i, 0); bR[2 + i][1] = ldB(cur, 2 + i, 1); }
    stageB(nxt, 0, t + 1);
    barrier_raw();
    LGKM0();
    MFMA16(0, 2);
    barrier_raw();
    // ---- phase 2: (m1,n1); ds: A-half1; stage A0(t+2) ----
#pragma unroll
    for (int i = 0; i < 4; ++i) { aR[i][0] = ldA(cur, 4 + i, 0); aR[i][1] = ldA(cur, 4 + i, 1); }
    stageA(cur, 0, t + 2);
    barrier_raw();
    LGKM0();
    MFMA16(4, 2);
    barrier_raw();
    // ---- phase 3: (m1,n0); no ds; stage B1(t+2); counted vmcnt ----
    stageB(cur, 1, t + 2);
    barrier_raw();
    MFMA16(4, 0);
    VMCNT4();
    barrier_raw();
  }

  // ---- epilogue: D frag col=lane&15, row=(lane>>4)*4+j ----
  float bv[4];
#pragma unroll
  for (int nt = 0; nt < 4; ++nt) bv[nt] = bias[n0 + (4 * nt + wc) * 16 + lrow];
#pragma unroll
  for (int mt = 0; mt < 8; ++mt) {
    const long rbase = m0 + (2 * mt + wr) * 16 + ((lane >> 4) << 2);
#pragma unroll
    for (int j = 0; j < 4; ++j) {
      OutT* cp = C + (rbase + j) * (long)NH + n0 + wc * 16 + lrow;
#pragma unroll
      for (int nt = 0; nt < 4; ++nt)
        cp[nt * 64] = (OutT)(acc[mt][nt][j] + bv[nt]);
    }
  }
#undef MFMA16
}

// ---------------- in-place scan: h[t] = relu(p[t] + w*h[t-1]) ----------------
template <typename PT>
__global__ __launch_bounds__(256)
void scan_inplace(PT* __restrict__ P, const float* __restrict__ w_hh) {
  const int c = blockIdx.x * 256 + threadIdx.x;   // 0..BH-1
  const float w = w_hh[c & (NH - 1)];
  PT* p = P + c;
  float h = 0.f;
  float v0 = (float)p[0L * BH];
  float v1 = (float)p[1L * BH];
  float v2 = (float)p[2L * BH];
  float v3 = (float)p[3L * BH];
  for (int t = 0; t < T_SEQ; t += 4) {
    float n0 = 0.f, n1 = 0.f, n2 = 0.f, n3 = 0.f;
    if (t + 4 < T_SEQ) {
      const PT* q = p + (long)(t + 4) * BH;
      n0 = (float)q[0L * BH];
      n1 = (float)q[1L * BH];
      n2 = (float)q[2L * BH];
      n3 = (float)q[3L * BH];
    }
    h = fmaxf(fmaf(w, h, v0), 0.f); p[(long)(t + 0) * BH] = (PT)h;
    h = fmaxf(fmaf(w, h, v1), 0.f); p[(long)(t + 1) * BH] = (PT)h;
    h = fmaxf(fmaf(w, h, v2), 0.f); p[(long)(t + 2) * BH] = (PT)h;
    h = fmaxf(fmaf(w, h, v3), 0.f); p[(long)(t + 3) * BH] = (PT)h;
    v0 = n0; v1 = n1; v2 = n2; v3 = n3;
  }
}

extern "C" void kernel_launch(void* const* d_in, const int* in_sizes, int n_in,
                              void* d_out, int out_size, void* d_ws, size_t ws_size,
                              hipStream_t stream) {
  const float* x     = (const float*)d_in[0];   // [1024,64,512]
  const float* w_ih0 = (const float*)d_in[1];   // [2048,512]
  const float* w_hh0 = (const float*)d_in[2];   // [2048]
  const float* b0    = (const float*)d_in[3];   // [2048]
  const float* w_ih1 = (const float*)d_in[4];   // [2048,2048]
  const float* w_hh1 = (const float*)d_in[5];   // [2048]
  const float* b1    = (const float*)d_in[6];   // [2048]
  float* out = (float*)d_out;                   // [1024,64,2048]

  char* ws = (char*)d_ws;
  f16* x16   = (f16*)(ws);                 // 64 MiB
  f16* w0_16 = (f16*)(ws + 67108864);      //  2 MiB
  f16* w1_16 = (f16*)(ws + 69206016);      //  8 MiB
  f16* P     = (f16*)(ws + 77594624);      // 256 MiB

  cvt_f16x4<<<2048, 256, 0, stream>>>(x,     x16,   33554432 / 4);
  cvt_f16x4<<<1024, 256, 0, stream>>>(w_ih0, w0_16, 1048576 / 4);
  cvt_f16x4<<<2048, 256, 0, stream>>>(w_ih1, w1_16, 4194304 / 4);

  // grid = (M/256)*(N/256) = 256*8 = 2048 blocks, 512 threads
  gemm8<NI, f16><<<2048, 512, 0, stream>>>(x16, w0_16, b0, P);
  scan_inplace<f16><<<BH / 256, 256, 0, stream>>>(P, w_hh0);
  gemm8<NH, float><<<2048, 512, 0, stream>>>(P, w1_16, b1, out);
  scan_inplace<float><<<BH / 256, 256, 0, stream>>>(out, w_hh1);
}

// Round 3
// 985.094 us; speedup vs baseline: 1.3930x; 1.1761x over previous
//
#include <hip/hip_runtime.h>

// IndRNN: two layers of (GEMM pre-projection + elementwise scan).
//   T=1024, B=64, I=512, H=2048.
// R3: GEMM1 writes fp16 pre1 (halves epilogue write); scan1 reads fp16,
// writes fp32 d_out; scans deepened to 8-deep prefetch; cvt launches merged.
// fp16-pre1 path guarded on ws_size (needs 586 MiB), else fp32 fallback.

#define T_SEQ 1024
#define NB 64
#define NI 512
#define NH 2048
#define BH (NB * NH)
#define M_ROWS (T_SEQ * NB)

typedef _Float16 f16;
typedef __attribute__((ext_vector_type(8))) _Float16 f16x8;
typedef __attribute__((ext_vector_type(4))) _Float16 f16x4;
typedef __attribute__((ext_vector_type(4))) float f32x4;

__device__ __forceinline__ void gload_lds16(const f16* g, const f16* lds) {
  __builtin_amdgcn_global_load_lds(
      (const __attribute__((address_space(1))) unsigned int*)g,
      (__attribute__((address_space(3))) unsigned int*)lds, 16, 0, 0);
}
__device__ __forceinline__ void barrier_raw() {
  __builtin_amdgcn_sched_barrier(0);
  __builtin_amdgcn_s_barrier();
  __builtin_amdgcn_sched_barrier(0);
}
// rule 18: inline-asm lgkmcnt(0) needs a following sched_barrier(0)
#define LGKM0()                                        \
  do {                                                 \
    asm volatile("s_waitcnt lgkmcnt(0)" ::: "memory"); \
    __builtin_amdgcn_sched_barrier(0);                 \
  } while (0)
#define VMCNT4() asm volatile("s_waitcnt vmcnt(4)" ::: "memory")

// ---------------- fp32 -> fp16 conversion, all 3 inputs in one launch -------
__global__ __launch_bounds__(256)
void cvt_all(const float* __restrict__ x, const float* __restrict__ w0,
             const float* __restrict__ w1, f16* __restrict__ x16,
             f16* __restrict__ w0_16, f16* __restrict__ w1_16) {
  constexpr int N0 = 33554432 / 4, N1 = 1048576 / 4, N2 = 4194304 / 4;
  int i = blockIdx.x * 256 + threadIdx.x;
  const int stride = gridDim.x * 256;
  for (; i < N0 + N1 + N2; i += stride) {
    const float* src; f16* dst; int j;
    if (i < N0)            { src = x;  dst = x16;   j = i; }
    else if (i < N0 + N1)  { src = w0; dst = w0_16; j = i - N0; }
    else                   { src = w1; dst = w1_16; j = i - N0 - N1; }
    f32x4 v = ((const f32x4*)src)[j];
    f16x4 h;
    h[0] = (f16)v[0]; h[1] = (f16)v[1]; h[2] = (f16)v[2]; h[3] = (f16)v[3];
    ((f16x4*)dst)[j] = h;
  }
}

// ------- GEMM: C[M,2048] = A[M,K] * Bt[2048,K]^T + bias, 8-phase 256^2 -------
// Wave (wr,wc): wr=wid>>2 (2 M-groups), wc=wid&3 (4 N-groups).
// m-tile mt(0..7) -> C rows (2*mt+wr)*16; A-half = mt>>2 (interleave-by-16).
// n-tile nt(0..3) -> C cols (4*nt+wc)*16; B-half = nt>>1.
// Phases per K-tile: (m0,n0)(m0,n1)(m1,n1)(m1,n0); stages: A1(t+1), B0(t+1),
// A0(t+2), B1(t+2); vmcnt(4) at phase 3 only.
template <int K, typename OutT>
__global__ __launch_bounds__(512, 2)
void gemm8(const f16* __restrict__ A, const f16* __restrict__ Bt,
           const float* __restrict__ bias, OutT* __restrict__ C) {
  constexpr int NT = K / 64;
  __shared__ f16 sA[2][2][128 * 64];   // [buf][half][row 128][k 64]
  __shared__ f16 sB[2][2][128 * 64];

  const int tid = threadIdx.x, wid = tid >> 6, lane = tid & 63;
  int id = (int)blockIdx.x;
  id = (id & 7) * 256 + (id >> 3);          // XCD swizzle (2048 % 8 == 0)
  const int bn = id & 7, bm = id >> 3;
  const long m0 = (long)bm * 256, n0 = (long)bn * 256;

  const int wr = wid >> 2, wc = wid & 3;
  const int lrow = lane & 15, lk = (lane >> 4) * 8;

  // ds_read byte offsets: L = (tilebase) + ks*64 + T; phys = L ^ ((row&7)<<4).
  const int xorv = (lrow & 7) << 4;
  const int TxA = (((wr * 16 + lrow) * 128) + lk * 2) ^ xorv;
  const int TxB = (((wc * 16 + lrow) * 128) + lk * 2) ^ xorv;

  auto ldA = [&](int buf, int mt, int ks) -> f16x8 {
    const char* p = (const char*)&sA[buf][mt >> 2][0];
    return *(const f16x8*)(p + (mt & 3) * 4096 + (TxA ^ (ks << 6)));
  };
  auto ldB = [&](int buf, int nt, int ks) -> f16x8 {
    const char* p = (const char*)&sB[buf][nt >> 1][0];
    return *(const f16x8*)(p + (nt & 1) * 8192 + (TxB ^ (ks << 6)));
  };

  // staging: LDS dest linear (base + lane*16 by HW); source pre-swizzled.
  const int srow = wid * 8 + (lane >> 3);
  const int scol = ((lane & 7) ^ ((lane >> 3) & 7)) * 8;
  const int ldst = wid * 512;   // f16 elements; +4096 for inst 1

  auto stageA = [&](int buf, int h, int kt) {
    if (kt >= NT) kt = NT - 1;   // tail clamp: lands in a dead buffer
    const f16* g = A + (m0 + h * 128 + srow) * (long)K + kt * 64 + scol;
    gload_lds16(g,                &sA[buf][h][ldst]);
    gload_lds16(g + 64 * (long)K, &sA[buf][h][ldst + 4096]);
  };
  auto stageB = [&](int buf, int h, int kt) {
    if (kt >= NT) kt = NT - 1;
    const f16* g = Bt + (n0 + h * 128 + srow) * (long)K + kt * 64 + scol;
    gload_lds16(g,                &sB[buf][h][ldst]);
    gload_lds16(g + 64 * (long)K, &sB[buf][h][ldst + 4096]);
  };

  f32x4 acc[8][4] = {};
  f16x8 aR[4][2], bR[4][2];

#define MFMA16(MBASE, NBASE)                                                   \
  __builtin_amdgcn_s_setprio(1);                                               \
  _Pragma("unroll") for (int mi = 0; mi < 4; ++mi)                             \
      _Pragma("unroll") for (int ni = 0; ni < 2; ++ni)                         \
          _Pragma("unroll") for (int ks = 0; ks < 2; ++ks)                     \
              acc[MBASE + mi][NBASE + ni] =                                    \
                  __builtin_amdgcn_mfma_f32_16x16x32_f16(                      \
                      aR[mi][ks], bR[NBASE + ni][ks],                          \
                      acc[MBASE + mi][NBASE + ni], 0, 0, 0);                   \
  __builtin_amdgcn_s_setprio(0);

  // prologue — queue order must match steady state:
  stageA(0, 0, 0);
  stageB(0, 1, 0);
  stageA(0, 1, 0);
  stageB(0, 0, 0);
  stageA(1, 0, 1);
  stageB(1, 1, 1);
  VMCNT4();
  barrier_raw();

  for (int t = 0; t < NT; ++t) {
    const int cur = t & 1, nxt = cur ^ 1;
    // ---- phase 0: (m0,n0); ds: A-half0 + B-half0; stage A1(t+1) ----
#pragma unroll
    for (int i = 0; i < 4; ++i) { aR[i][0] = ldA(cur, i, 0); aR[i][1] = ldA(cur, i, 1); }
#pragma unroll
    for (int i = 0; i < 2; ++i) { bR[i][0] = ldB(cur, i, 0); bR[i][1] = ldB(cur, i, 1); }
    stageA(nxt, 1, t + 1);
    barrier_raw();
    LGKM0();
    MFMA16(0, 0);
    barrier_raw();
    // ---- phase 1: (m0,n1); ds: B-half1; stage B0(t+1) ----
#pragma unroll
    for (int i = 0; i < 2; ++i) { bR[2 + i][0] = ldB(cur, 2 + i, 0); bR[2 + i][1] = ldB(cur, 2 + i, 1); }
    stageB(nxt, 0, t + 1);
    barrier_raw();
    LGKM0();
    MFMA16(0, 2);
    barrier_raw();
    // ---- phase 2: (m1,n1); ds: A-half1; stage A0(t+2) ----
#pragma unroll
    for (int i = 0; i < 4; ++i) { aR[i][0] = ldA(cur, 4 + i, 0); aR[i][1] = ldA(cur, 4 + i, 1); }
    stageA(cur, 0, t + 2);
    barrier_raw();
    LGKM0();
    MFMA16(4, 2);
    barrier_raw();
    // ---- phase 3: (m1,n0); no ds; stage B1(t+2); counted vmcnt ----
    stageB(cur, 1, t + 2);
    barrier_raw();
    MFMA16(4, 0);
    VMCNT4();
    barrier_raw();
  }

  // ---- epilogue: D frag col=lane&15, row=(lane>>4)*4+j ----
  float bv[4];
#pragma unroll
  for (int nt = 0; nt < 4; ++nt) bv[nt] = bias[n0 + (4 * nt + wc) * 16 + lrow];
#pragma unroll
  for (int mt = 0; mt < 8; ++mt) {
    const long rbase = m0 + (2 * mt + wr) * 16 + ((lane >> 4) << 2);
#pragma unroll
    for (int j = 0; j < 4; ++j) {
      OutT* cp = C + (rbase + j) * (long)NH + n0 + wc * 16 + lrow;
#pragma unroll
      for (int nt = 0; nt < 4; ++nt)
        cp[nt * 64] = (OutT)(acc[mt][nt][j] + bv[nt]);
    }
  }
#undef MFMA16
}

// ------------- scan: h[t] = relu(pre[t] + w*h[t-1]); out[t] = h -------------
// One thread per (b,h) channel; fp32 state in regs; 8-deep software prefetch
// (~16 KB in flight per CU at 8 waves/CU, covers ~900 cy HBM latency).
// No __restrict__: in==out for the in-place layer-0 use; affine offsets let
// the compiler disambiguate the t+8 loads from the t stores.
template <typename InT, typename OutT>
__global__ __launch_bounds__(256)
void scan_k(const InT* in, OutT* out, const float* __restrict__ w_hh) {
  const int c = blockIdx.x * 256 + threadIdx.x;   // 0..BH-1
  const float w = w_hh[c & (NH - 1)];
  const InT* pi = in + c;
  OutT* po = out + c;
  float h = 0.f, v[8], n[8];
#pragma unroll
  for (int j = 0; j < 8; ++j) v[j] = (float)pi[(long)j * BH];
  for (int t = 0; t < T_SEQ; t += 8) {
    if (t + 8 < T_SEQ) {
#pragma unroll
      for (int j = 0; j < 8; ++j) n[j] = (float)pi[(long)(t + 8 + j) * BH];
    } else {
#pragma unroll
      for (int j = 0; j < 8; ++j) n[j] = 0.f;
    }
#pragma unroll
    for (int j = 0; j < 8; ++j) {
      h = fmaxf(fmaf(w, h, v[j]), 0.f);
      po[(long)(t + j) * BH] = (OutT)h;
      v[j] = n[j];
    }
  }
}

extern "C" void kernel_launch(void* const* d_in, const int* in_sizes, int n_in,
                              void* d_out, int out_size, void* d_ws, size_t ws_size,
                              hipStream_t stream) {
  const float* x     = (const float*)d_in[0];   // [1024,64,512]
  const float* w_ih0 = (const float*)d_in[1];   // [2048,512]
  const float* w_hh0 = (const float*)d_in[2];   // [2048]
  const float* b0    = (const float*)d_in[3];   // [2048]
  const float* w_ih1 = (const float*)d_in[4];   // [2048,2048]
  const float* w_hh1 = (const float*)d_in[5];   // [2048]
  const float* b1    = (const float*)d_in[6];   // [2048]
  float* out = (float*)d_out;                   // [1024,64,2048]

  char* ws = (char*)d_ws;
  f16* x16   = (f16*)(ws);                 // 64 MiB
  f16* w0_16 = (f16*)(ws + 67108864);      //  2 MiB
  f16* w1_16 = (f16*)(ws + 69206016);      //  8 MiB
  f16* P     = (f16*)(ws + 77594624);      // 256 MiB (pre0 -> h0, in-place)
  f16* P2    = (f16*)(ws + 346030080);     // 256 MiB (pre1 fp16), if ws allows
  const bool p2_f16 = ws_size >= (size_t)346030080 + 268435456;

  cvt_all<<<2048, 256, 0, stream>>>(x, w_ih0, w_ih1, x16, w0_16, w1_16);

  // grid = (M/256)*(N/256) = 256*8 = 2048 blocks, 512 threads
  gemm8<NI, f16><<<2048, 512, 0, stream>>>(x16, w0_16, b0, P);
  scan_k<f16, f16><<<BH / 256, 256, 0, stream>>>(P, P, w_hh0);
  if (p2_f16) {
    gemm8<NH, f16><<<2048, 512, 0, stream>>>(P, w1_16, b1, P2);
    scan_k<f16, float><<<BH / 256, 256, 0, stream>>>(P2, out, w_hh1);
  } else {
    gemm8<NH, float><<<2048, 512, 0, stream>>>(P, w1_16, b1, out);
    scan_k<float, float><<<BH / 256, 256, 0, stream>>>(out, out, w_hh1);
  }
}